// Round 9
// baseline (364.775 us; speedup 1.0000x reference)
//
#include <hip/hip_runtime.h>
#include <hip/hip_fp16.h>

// ---------------------------------------------------------------------------
// GCNEncoder: 3-layer GCN with symmetric norm and self-loops.
//   per layer: h = (x * out_norm) @ W ; agg = segsum(h[src], dst) + h (self)
//              out = agg * in_norm + b ; relu (layers 1,2)
// CSR build (by dst) -> aggregation is pure gather.
// R2: FAILED — device atomics have a ~20 G/s write-through floor.
// R3: LDS-atomic radix partition (zero device atomics).
// R4: inter-layer tables fp16 (256 B gather rows).   R5: GEMMs on MFMA.
// R6: packed scatter payloads + single concatenated scan.
// R7: scatter via block-local LDS counting sort (coalesced run writes).
// R8: agg+next-GEMM fused (agg epilogue feeds the MFMA A-tile in LDS) —
//     kills 102 MB of h-table round-trip streaming + 2 launches.
// ---------------------------------------------------------------------------

#define NFEAT 128
#define BBITS 8
#define BSZ 256                     // nodes per bucket
#define EPB 4096                    // edges per partition block

union H8 { float4 f4; __half2 h2[4]; };   // 8 halves = 16 B

using half8v = __attribute__((ext_vector_type(8))) _Float16;
using f32x4  = __attribute__((ext_vector_type(4))) float;

// --- Pass 1: per-block LDS histograms; hist2 = [D part | S part], bucket-major ---
__global__ __launch_bounds__(256) void hist_kernel(const int* __restrict__ src,
                                                   const int* __restrict__ dst,
                                                   int* __restrict__ hist2,
                                                   int NB, int nblk, int nh, int E) {
    __shared__ int hd[512], hs[512];
    const int t = threadIdx.x, b = blockIdx.x;
    for (int u = t; u < 512; u += 256) { hd[u] = 0; hs[u] = 0; }
    __syncthreads();
    const int base4 = b * (EPB / 4);
    #pragma unroll
    for (int j = 0; j < 4; ++j) {
        int i4 = base4 + j * 256 + t;
        int e0 = i4 * 4;
        if (e0 + 3 < E) {
            int4 s = ((const int4*)src)[i4];
            int4 d = ((const int4*)dst)[i4];
            atomicAdd(&hs[s.x >> BBITS], 1); atomicAdd(&hs[s.y >> BBITS], 1);
            atomicAdd(&hs[s.z >> BBITS], 1); atomicAdd(&hs[s.w >> BBITS], 1);
            atomicAdd(&hd[d.x >> BBITS], 1); atomicAdd(&hd[d.y >> BBITS], 1);
            atomicAdd(&hd[d.z >> BBITS], 1); atomicAdd(&hd[d.w >> BBITS], 1);
        } else {
            for (int e = e0; e < E && e < e0 + 4; ++e) {
                atomicAdd(&hs[src[e] >> BBITS], 1);
                atomicAdd(&hd[dst[e] >> BBITS], 1);
            }
        }
    }
    __syncthreads();
    for (int u = t; u < NB; u += 256) {
        hist2[u * nblk + b]      = hd[u];
        hist2[nh + u * nblk + b] = hs[u];
    }
}

// --- 3-kernel exclusive scan, 2 elements/thread (512/block), in-place ---
__global__ __launch_bounds__(256) void scan1_kernel(int* __restrict__ data,
                                                    int* __restrict__ blk_sum, int n) {
    const int tid = threadIdx.x, lane = tid & 63, wid = tid >> 6;  // 4 waves
    const int i2 = blockIdx.x * 256 + tid;
    int a = 0, b = 0;
    if (2 * i2 + 1 < n)      { int2 v = ((const int2*)data)[i2]; a = v.x; b = v.y; }
    else if (2 * i2 < n)     { a = data[2 * i2]; }
    int s = a + b;
    int incl = s;
    #pragma unroll
    for (int off = 1; off < 64; off <<= 1) {
        int t2 = __shfl_up(incl, off, 64);
        if (lane >= off) incl += t2;
    }
    __shared__ int ws[4];
    if (lane == 63) ws[wid] = incl;
    __syncthreads();
    int woff = 0;
    #pragma unroll
    for (int w = 0; w < 3; ++w) if (w < wid) woff += ws[w];
    int pref = woff + incl - s;
    if (2 * i2 < n)     data[2 * i2]     = pref;
    if (2 * i2 + 1 < n) data[2 * i2 + 1] = pref + a;
    if (tid == 0) blk_sum[blockIdx.x] = ws[0] + ws[1] + ws[2] + ws[3];
}

__global__ __launch_bounds__(1024) void scan2_kernel(int* __restrict__ blk, int nb) {
    const int tid = threadIdx.x, lane = tid & 63, wid = tid >> 6;  // 16 waves
    int v = (tid < nb) ? blk[tid] : 0;
    int incl = v;
    #pragma unroll
    for (int off = 1; off < 64; off <<= 1) {
        int t = __shfl_up(incl, off, 64);
        if (lane >= off) incl += t;
    }
    __shared__ int ws[16];
    if (lane == 63) ws[wid] = incl;
    __syncthreads();
    int woff = 0;
    #pragma unroll
    for (int w = 0; w < 15; ++w) if (w < wid) woff += ws[w];
    if (tid < nb) blk[tid] = woff + incl - v;
}

__global__ __launch_bounds__(256) void scan3_kernel(int* __restrict__ data,
                                                    const int* __restrict__ blk, int n) {
    const int i2 = blockIdx.x * 256 + threadIdx.x;
    int add = blk[blockIdx.x];
    if (2 * i2 < n)     data[2 * i2]     += add;
    if (2 * i2 + 1 < n) data[2 * i2 + 1] += add;
}

// --- Pass 2: scatter via block-local LDS counting sort -> coalesced run writes ---
__global__ __launch_bounds__(512) void scatter_kernel(const int* __restrict__ src,
                                                      const int* __restrict__ dst,
                                                      const int* __restrict__ hist2,
                                                      unsigned int* __restrict__ dstP,
                                                      unsigned char* __restrict__ srcB,
                                                      int NB, int nblk, int nh, int E) {
    __shared__ int hd[512], hs[512], startD[512], startS[512], baseD[512], baseS[512];
    __shared__ int ws[8];
    __shared__ unsigned int   payD[EPB];   // 16 KB
    __shared__ unsigned short kD[EPB];     // 8 KB
    __shared__ unsigned char  sV[EPB];     // 4 KB
    __shared__ unsigned short kS[EPB];     // 8 KB
    const int t = threadIdx.x, b = blockIdx.x;
    const int lane = t & 63, wid = t >> 6;                 // 8 waves
    hd[t] = 0; hs[t] = 0;
    for (int u = t; u < NB; u += 512) {
        baseD[u] = hist2[u * nblk + b];
        baseS[u] = hist2[nh + u * nblk + b] - E;           // S scanned after D (sum D = E)
    }
    __syncthreads();

    const int e0 = b * EPB;
    const int nE = min(EPB, E - e0);
    int se[8], de[8], rD[8], rS[8];
    const int be = e0 + t * 8;
    if (be + 7 < E) {
        int4 s0 = ((const int4*)src)[(be >> 2)];
        int4 s1 = ((const int4*)src)[(be >> 2) + 1];
        int4 d0 = ((const int4*)dst)[(be >> 2)];
        int4 d1 = ((const int4*)dst)[(be >> 2) + 1];
        se[0]=s0.x; se[1]=s0.y; se[2]=s0.z; se[3]=s0.w;
        se[4]=s1.x; se[5]=s1.y; se[6]=s1.z; se[7]=s1.w;
        de[0]=d0.x; de[1]=d0.y; de[2]=d0.z; de[3]=d0.w;
        de[4]=d1.x; de[5]=d1.y; de[6]=d1.z; de[7]=d1.w;
    } else {
        #pragma unroll
        for (int j = 0; j < 8; ++j) {
            se[j] = (be + j < E) ? src[be + j] : 0;
            de[j] = (be + j < E) ? dst[be + j] : 0;
        }
    }
    #pragma unroll
    for (int j = 0; j < 8; ++j) {
        if (be + j < E) {
            rD[j] = atomicAdd(&hd[de[j] >> BBITS], 1);
            rS[j] = atomicAdd(&hs[se[j] >> BBITS], 1);
        }
    }
    __syncthreads();
    {
        int v = hd[t], incl = v;
        #pragma unroll
        for (int o = 1; o < 64; o <<= 1) {
            int x = __shfl_up(incl, o, 64);
            if (lane >= o) incl += x;
        }
        if (lane == 63) ws[wid] = incl;
        __syncthreads();
        int woff = 0;
        #pragma unroll
        for (int w = 0; w < 7; ++w) if (w < wid) woff += ws[w];
        startD[t] = woff + incl - v;
    }
    __syncthreads();
    {
        int v = hs[t], incl = v;
        #pragma unroll
        for (int o = 1; o < 64; o <<= 1) {
            int x = __shfl_up(incl, o, 64);
            if (lane >= o) incl += x;
        }
        if (lane == 63) ws[wid] = incl;
        __syncthreads();
        int woff = 0;
        #pragma unroll
        for (int w = 0; w < 7; ++w) if (w < wid) woff += ws[w];
        startS[t] = woff + incl - v;
    }
    __syncthreads();
    #pragma unroll
    for (int j = 0; j < 8; ++j) {
        if (be + j < E) {
            int kd = de[j] >> BBITS;
            int p  = startD[kd] + rD[j];
            payD[p] = ((unsigned int)(de[j] & (BSZ - 1)) << 24) | (unsigned int)se[j];
            kD[p]   = (unsigned short)kd;
            int ks = se[j] >> BBITS;
            int q  = startS[ks] + rS[j];
            sV[q] = (unsigned char)(se[j] & (BSZ - 1));
            kS[q] = (unsigned short)ks;
        }
    }
    __syncthreads();
    for (int p = t; p < nE; p += 512) {
        int k = kD[p];
        dstP[baseD[k] + (p - startD[k])] = payD[p];
        int k2 = kS[p];
        srcB[baseS[k2] + (p - startS[k2])] = sV[p];
    }
}

// --- Pass 3: per-bucket CSR finalize + degrees + norms (all LDS) ---
__global__ __launch_bounds__(256) void bucket_kernel(const unsigned int* __restrict__ dstP,
                                                     const unsigned char* __restrict__ srcB,
                                                     const int* __restrict__ hist2,
                                                     int* __restrict__ row_ptr,
                                                     int* __restrict__ col_idx,
                                                     float* __restrict__ in_norm,
                                                     float* __restrict__ out_norm,
                                                     int N, int NB, int nblk, int nh, int E) {
    __shared__ int cnt[BSZ], scnt[BSZ], start[BSZ], off[BSZ];
    __shared__ int ws[4];
    const int k = blockIdx.x, t = threadIdx.x;
    const int node0 = k << BBITS;
    cnt[t] = 0; scnt[t] = 0; off[t] = 0;
    __syncthreads();
    const int bB = hist2[k * nblk];
    const int bE = (k + 1 < NB) ? hist2[(k + 1) * nblk] : E;
    const int sB = hist2[nh + k * nblk] - E;
    const int sE = ((k + 1 < NB) ? hist2[nh + (k + 1) * nblk] : 2 * E) - E;
    for (int i = bB + t; i < bE; i += 256) atomicAdd(&cnt[dstP[i] >> 24], 1);
    for (int i = sB + t; i < sE; i += 256) atomicAdd(&scnt[srcB[i]], 1);
    __syncthreads();
    const int lane = t & 63, wid = t >> 6;
    int v = cnt[t];
    int incl = v;
    #pragma unroll
    for (int o = 1; o < 64; o <<= 1) {
        int x = __shfl_up(incl, o, 64);
        if (lane >= o) incl += x;
    }
    if (lane == 63) ws[wid] = incl;
    __syncthreads();
    int woff = 0;
    #pragma unroll
    for (int w = 0; w < 3; ++w) if (w < wid) woff += ws[w];
    start[t] = woff + incl - v;
    {
        int node = node0 + t;
        if (node < N) {
            row_ptr[node] = bB + start[t];
            in_norm[node]  = rsqrtf((float)(v + 1));          // +1 self-loop
            out_norm[node] = rsqrtf((float)(scnt[t] + 1));
        }
    }
    if (k == 0 && t == 0) row_ptr[N] = E;
    __syncthreads();
    for (int i = bB + t; i < bE; i += 256) {
        unsigned int pv = dstP[i];
        int local = pv >> 24;
        int r = atomicAdd(&off[local], 1);
        col_idx[bB + start[local] + r] = (int)(pv & 0xFFFFFFu);
    }
}

// --- all three W [K][Ncols] fp32 -> Wt [Ncols][K=128] fp16 in one launch ---
__global__ void wt_all_kernel(const float* __restrict__ W1, const float* __restrict__ W2,
                              const float* __restrict__ W3, __half* __restrict__ Wt1,
                              __half* __restrict__ Wt2, __half* __restrict__ Wt3) {
    int b = blockIdx.x, k = threadIdx.x;
    if (b < 128)      Wt1[b * 128 + k] = __float2half(W1[k * 128 + b]);
    else if (b < 256) { int n = b - 128; Wt2[n * 128 + k] = __float2half(W2[k * 128 + n]); }
    else              { int n = b - 256; Wt3[n * 128 + k] = __float2half(W3[k * 64 + n]); }
}

// --- MFMA GEMM (layer 1 only): h[64 x 128] = fp16(x_f32 * out_norm) @ W ---
__global__ __launch_bounds__(256) void mfma_gemm_kernel(const float* __restrict__ x,
                                                        const __half* __restrict__ Wt,
                                                        const float* __restrict__ out_norm,
                                                        __half* __restrict__ h, int n_rows) {
    constexpr int BN = 128, NT = BN / 16;
    __shared__ __half As[64][136];
    __shared__ __half Bs[BN][136];
    const int tid  = threadIdx.x;
    const int row0 = blockIdx.x * 64;

    {
        int r  = tid >> 2;                 // 0..63
        int c0 = (tid & 3) * 32;           // 0,32,64,96
        int grow = row0 + r;
        if (grow < n_rows) {
            float norm = out_norm[grow];
            const float* xp = x + (size_t)grow * NFEAT + c0;
            #pragma unroll
            for (int j = 0; j < 4; ++j) {
                float4 p0 = *(const float4*)(xp + j * 8);
                float4 p1 = *(const float4*)(xp + j * 8 + 4);
                H8 u;
                u.h2[0] = __floats2half2_rn(p0.x * norm, p0.y * norm);
                u.h2[1] = __floats2half2_rn(p0.z * norm, p0.w * norm);
                u.h2[2] = __floats2half2_rn(p1.x * norm, p1.y * norm);
                u.h2[3] = __floats2half2_rn(p1.z * norm, p1.w * norm);
                *(float4*)&As[r][c0 + j * 8] = u.f4;
            }
        } else {
            H8 z; z.f4 = make_float4(0.f, 0.f, 0.f, 0.f);
            #pragma unroll
            for (int j = 0; j < 4; ++j) *(float4*)&As[r][c0 + j * 8] = z.f4;
        }
    }
    {
        int wr = tid / 2;
        int wc = (tid % 2) * 64;
        const __half* wp = Wt + wr * 128 + wc;
        #pragma unroll
        for (int j = 0; j < 8; ++j)
            *(float4*)&Bs[wr][wc + j * 8] = *(const float4*)(wp + j * 8);
    }
    __syncthreads();

    const int lane = tid & 63, wid = tid >> 6;
    const int lr = lane & 15, quad = lane >> 4;
    const int koff = quad * 8;
    f32x4 acc[NT];
    #pragma unroll
    for (int t = 0; t < NT; ++t) acc[t] = (f32x4){0.f, 0.f, 0.f, 0.f};

    #pragma unroll
    for (int ks = 0; ks < 4; ++ks) {
        half8v a = *(const half8v*)&As[wid * 16 + lr][ks * 32 + koff];
        #pragma unroll
        for (int nt = 0; nt < NT; ++nt) {
            half8v b = *(const half8v*)&Bs[nt * 16 + lr][ks * 32 + koff];
            acc[nt] = __builtin_amdgcn_mfma_f32_16x16x32_f16(a, b, acc[nt], 0, 0, 0);
        }
    }

    #pragma unroll
    for (int nt = 0; nt < NT; ++nt) {
        #pragma unroll
        for (int r = 0; r < 4; ++r) {
            int row = row0 + wid * 16 + quad * 4 + r;
            if (row < n_rows)
                h[(size_t)row * BN + nt * 16 + lr] = __float2half(acc[nt][r]);
        }
    }
}

// --- R8: fused agg + GEMM. Block = 64 dst nodes.
// Phase A: gather-agg hin (128-wide), epilogue relu(acc*inn+b)*onorm -> As fp16.
// Phase B: MFMA As @ Wt(BN x 128) -> hout.
template <int BN>
__global__ __launch_bounds__(256) void fused_agg_gemm_kernel(
        const __half* __restrict__ hin, const int* __restrict__ row_ptr,
        const int* __restrict__ col_idx, const float* __restrict__ in_norm,
        const float* __restrict__ out_norm, const float* __restrict__ bias,
        const __half* __restrict__ Wt, __half* __restrict__ hout, int n) {
    constexpr int NT = BN / 16;
    __shared__ __half As[64][136];
    __shared__ __half Bs[BN][136];
    const int tid   = threadIdx.x;
    const int node0 = blockIdx.x * 64;

    // stage Wt first (loads fly under the gather loop)
    {
        constexpr int TPR = 256 / BN;              // 2 (BN=128) or 4 (BN=64)
        constexpr int CH  = 128 / TPR;
        int wr = tid / TPR;
        int wc = (tid % TPR) * CH;
        const __half* wp = Wt + wr * 128 + wc;
        #pragma unroll
        for (int j = 0; j < CH / 8; ++j)
            *(float4*)&Bs[wr][wc + j * 8] = *(const float4*)(wp + j * 8);
    }

    // Phase A: 4 passes x 16 nodes, 16 threads/node (8 feats each)
    const int sub = tid >> 4;          // 0..15
    const int c   = (tid & 15) * 8;
    #pragma unroll
    for (int p = 0; p < 4; ++p) {
        const int nl   = p * 16 + sub;
        const int node = node0 + nl;
        if (node < n) {
            float acc[8];
            {
                H8 u; u.f4 = *(const float4*)(hin + (size_t)node * 128 + c);  // self-loop
                #pragma unroll
                for (int q = 0; q < 4; ++q) {
                    float2 pp = __half22float2(u.h2[q]);
                    acc[q * 2] = pp.x; acc[q * 2 + 1] = pp.y;
                }
            }
            int e  = row_ptr[node];
            int e1 = row_ptr[node + 1];
            for (; e + 3 < e1; e += 4) {
                int s0 = col_idx[e], s1 = col_idx[e + 1];
                int s2 = col_idx[e + 2], s3 = col_idx[e + 3];
                H8 u0, u1, u2, u3;
                u0.f4 = *(const float4*)(hin + (size_t)s0 * 128 + c);
                u1.f4 = *(const float4*)(hin + (size_t)s1 * 128 + c);
                u2.f4 = *(const float4*)(hin + (size_t)s2 * 128 + c);
                u3.f4 = *(const float4*)(hin + (size_t)s3 * 128 + c);
                #pragma unroll
                for (int q = 0; q < 4; ++q) {
                    float2 p0 = __half22float2(u0.h2[q]);
                    float2 p1 = __half22float2(u1.h2[q]);
                    float2 p2 = __half22float2(u2.h2[q]);
                    float2 p3 = __half22float2(u3.h2[q]);
                    acc[q * 2]     += (p0.x + p1.x) + (p2.x + p3.x);
                    acc[q * 2 + 1] += (p0.y + p1.y) + (p2.y + p3.y);
                }
            }
            for (; e < e1; ++e) {
                int s0 = col_idx[e];
                H8 u0; u0.f4 = *(const float4*)(hin + (size_t)s0 * 128 + c);
                #pragma unroll
                for (int q = 0; q < 4; ++q) {
                    float2 p0 = __half22float2(u0.h2[q]);
                    acc[q * 2] += p0.x; acc[q * 2 + 1] += p0.y;
                }
            }
            float inn = in_norm[node], onorm = out_norm[node];
            H8 o;
            #pragma unroll
            for (int q = 0; q < 4; ++q) {
                float r0 = fmaxf(acc[q * 2]     * inn + bias[c + q * 2],     0.0f) * onorm;
                float r1 = fmaxf(acc[q * 2 + 1] * inn + bias[c + q * 2 + 1], 0.0f) * onorm;
                o.h2[q] = __floats2half2_rn(r0, r1);
            }
            *(float4*)&As[nl][c] = o.f4;
        } else {
            H8 z; z.f4 = make_float4(0.f, 0.f, 0.f, 0.f);
            *(float4*)&As[nl][c] = z.f4;
        }
    }
    __syncthreads();

    // Phase B: MFMA
    const int lane = tid & 63, wid = tid >> 6;
    const int lr = lane & 15, quad = lane >> 4;
    const int koff = quad * 8;
    f32x4 acc[NT];
    #pragma unroll
    for (int t = 0; t < NT; ++t) acc[t] = (f32x4){0.f, 0.f, 0.f, 0.f};

    #pragma unroll
    for (int ks = 0; ks < 4; ++ks) {
        half8v a = *(const half8v*)&As[wid * 16 + lr][ks * 32 + koff];
        #pragma unroll
        for (int nt = 0; nt < NT; ++nt) {
            half8v b = *(const half8v*)&Bs[nt * 16 + lr][ks * 32 + koff];
            acc[nt] = __builtin_amdgcn_mfma_f32_16x16x32_f16(a, b, acc[nt], 0, 0, 0);
        }
    }

    #pragma unroll
    for (int nt = 0; nt < NT; ++nt) {
        #pragma unroll
        for (int r = 0; r < 4; ++r) {
            int row = node0 + wid * 16 + quad * 4 + r;
            if (row < n)
                hout[(size_t)row * BN + nt * 16 + lr] = __float2half(acc[nt][r]);
        }
    }
}

// Final aggregation (layer 3): out = (sum_in h[src] + h[node]) * in_norm + b, fp32 out
__global__ __launch_bounds__(256) void agg64_kernel(const __half* __restrict__ h,
                                                    const int* __restrict__ row_ptr,
                                                    const int* __restrict__ col_idx,
                                                    const float* __restrict__ in_norm,
                                                    const float* __restrict__ bias,
                                                    float* __restrict__ out, int n) {
    constexpr int DOUT = 64, TPN = DOUT / 8, NPB = 256 / TPN;
    const int tid  = threadIdx.x;
    const int sub  = tid / TPN;
    const int c    = (tid % TPN) * 8;
    const int node = blockIdx.x * NPB + sub;
    if (node >= n) return;

    float acc[8];
    {
        H8 u; u.f4 = *(const float4*)(h + (size_t)node * DOUT + c);
        #pragma unroll
        for (int q = 0; q < 4; ++q) {
            float2 p = __half22float2(u.h2[q]);
            acc[q * 2] = p.x; acc[q * 2 + 1] = p.y;
        }
    }
    int e  = row_ptr[node];
    int e1 = row_ptr[node + 1];
    for (; e + 3 < e1; e += 4) {
        int s0 = col_idx[e], s1 = col_idx[e + 1], s2 = col_idx[e + 2], s3 = col_idx[e + 3];
        H8 u0, u1, u2, u3;
        u0.f4 = *(const float4*)(h + (size_t)s0 * DOUT + c);
        u1.f4 = *(const float4*)(h + (size_t)s1 * DOUT + c);
        u2.f4 = *(const float4*)(h + (size_t)s2 * DOUT + c);
        u3.f4 = *(const float4*)(h + (size_t)s3 * DOUT + c);
        #pragma unroll
        for (int q = 0; q < 4; ++q) {
            float2 p0 = __half22float2(u0.h2[q]);
            float2 p1 = __half22float2(u1.h2[q]);
            float2 p2 = __half22float2(u2.h2[q]);
            float2 p3 = __half22float2(u3.h2[q]);
            acc[q * 2]     += (p0.x + p1.x) + (p2.x + p3.x);
            acc[q * 2 + 1] += (p0.y + p1.y) + (p2.y + p3.y);
        }
    }
    for (; e < e1; ++e) {
        int s0 = col_idx[e];
        H8 u0; u0.f4 = *(const float4*)(h + (size_t)s0 * DOUT + c);
        #pragma unroll
        for (int q = 0; q < 4; ++q) {
            float2 p0 = __half22float2(u0.h2[q]);
            acc[q * 2] += p0.x; acc[q * 2 + 1] += p0.y;
        }
    }
    float inn = in_norm[node];
    float4 o0, o1;
    o0.x = acc[0] * inn + bias[c + 0]; o0.y = acc[1] * inn + bias[c + 1];
    o0.z = acc[2] * inn + bias[c + 2]; o0.w = acc[3] * inn + bias[c + 3];
    o1.x = acc[4] * inn + bias[c + 4]; o1.y = acc[5] * inn + bias[c + 5];
    o1.z = acc[6] * inn + bias[c + 6]; o1.w = acc[7] * inn + bias[c + 7];
    *(float4*)(out + (size_t)node * DOUT + c)     = o0;
    *(float4*)(out + (size_t)node * DOUT + c + 4) = o1;
}

extern "C" void kernel_launch(void* const* d_in, const int* in_sizes, int n_in,
                              void* d_out, int out_size, void* d_ws, size_t ws_size,
                              hipStream_t stream) {
    const float* feat = (const float*)d_in[0];
    const int*   src  = (const int*)d_in[1];
    const int*   dst  = (const int*)d_in[2];
    const float* W1   = (const float*)d_in[3];
    const float* b1   = (const float*)d_in[4];
    const float* W2   = (const float*)d_in[5];
    const float* b2   = (const float*)d_in[6];
    const float* W3   = (const float*)d_in[7];
    const float* b3   = (const float*)d_in[8];

    const int N = in_sizes[0] / NFEAT;   // 100000
    const int E = in_sizes[1];           // 1600000

    const int NB   = (N + BSZ - 1) / BSZ;        // 391 buckets
    const int nblk = (E + EPB - 1) / EPB;        // 391 partition blocks
    const int nh   = NB * nblk;                  // hist elements per side
    const int n2   = 2 * nh;                     // concatenated [D|S]
    const int nsb  = (n2 + 511) / 512;           // scan blocks (<= 1024)

    char* ws = (char*)d_ws;
    auto alloc = [&](size_t bytes) {
        char* p = ws;
        ws += (bytes + 255) & ~(size_t)255;
        return p;
    };
    float* out_norm = (float*)alloc((size_t)N * 4);
    float* in_norm  = (float*)alloc((size_t)N * 4);
    int*   row_ptr  = (int*)alloc((size_t)(N + 1) * 4);
    int*   hist2    = (int*)alloc((size_t)n2 * 4);
    int*   blk_sum  = (int*)alloc((size_t)1024 * 4);
    __half* Wt1     = (__half*)alloc((size_t)128 * 128 * 2);
    __half* Wt2     = (__half*)alloc((size_t)128 * 128 * 2);
    __half* Wt3     = (__half*)alloc((size_t)64 * 128 * 2);
    int*   col_idx  = (int*)alloc((size_t)E * 4);
    // hA region also hosts the 2 packed partition arrays (E*4 + E = 8 MB <= 25.6 MB)
    __half* hA      = (__half*)alloc((size_t)N * NFEAT * 2);
    __half* hB      = (__half*)alloc((size_t)N * NFEAT * 2);
    unsigned int*  dstP = (unsigned int*)hA;
    unsigned char* srcB = (unsigned char*)(dstP + E);

    // --- weight transpose/convert (independent of graph chain) ---
    wt_all_kernel<<<320, 128, 0, stream>>>(W1, W2, W3, Wt1, Wt2, Wt3);

    // --- CSR build: hist -> scan(concat) -> scatter(LDS sort) -> bucket ---
    hist_kernel<<<nblk, 256, 0, stream>>>(src, dst, hist2, NB, nblk, nh, E);
    scan1_kernel<<<nsb, 256, 0, stream>>>(hist2, blk_sum, n2);
    scan2_kernel<<<1, 1024, 0, stream>>>(blk_sum, nsb);
    scan3_kernel<<<nsb, 256, 0, stream>>>(hist2, blk_sum, n2);
    scatter_kernel<<<nblk, 512, 0, stream>>>(src, dst, hist2, dstP, srcB, NB, nblk, nh, E);
    bucket_kernel<<<NB, 256, 0, stream>>>(dstP, srcB, hist2, row_ptr, col_idx,
                                          in_norm, out_norm, N, NB, nblk, nh, E);

    const int gb = (N + 63) / 64;
    // layer 1 GEMM (feat fp32 -> hA fp16)
    mfma_gemm_kernel<<<gb, 256, 0, stream>>>(feat, Wt1, out_norm, hA, N);
    // fused: agg1(hA) + relu + norms + GEMM2 -> hB
    fused_agg_gemm_kernel<128><<<gb, 256, 0, stream>>>(hA, row_ptr, col_idx, in_norm,
                                                       out_norm, b1, Wt2, hB, N);
    // fused: agg2(hB) + relu + norms + GEMM3 -> hA (N x 64 fp16)
    fused_agg_gemm_kernel<64><<<gb, 256, 0, stream>>>(hB, row_ptr, col_idx, in_norm,
                                                      out_norm, b2, Wt3, hA, N);
    // final agg (64-wide) -> d_out fp32
    agg64_kernel<<<(N + 31) / 32, 256, 0, stream>>>(hA, row_ptr, col_idx, in_norm, b3,
                                                    (float*)d_out, N);
}

// Round 10
// 364.057 us; speedup vs baseline: 1.0020x; 1.0020x over previous
//
#include <hip/hip_runtime.h>
#include <hip/hip_fp16.h>

// ---------------------------------------------------------------------------
// GCNEncoder: 3-layer GCN with symmetric norm and self-loops.
//   per layer: h = (x * out_norm) @ W ; agg = segsum(h[src], dst) + h (self)
//              out = agg * in_norm + b ; relu (layers 1,2)
// CSR build (by dst) -> aggregation is pure gather.
// R2: FAILED — device atomics have a ~20 G/s write-through floor.
// R3: LDS-atomic radix partition (zero device atomics).
// R4: inter-layer tables fp16 (256 B gather rows).   R5: GEMMs on MFMA.
// R6: packed scatter payloads + single concatenated scan.
// R7: scatter via block-local LDS counting sort (coalesced run writes).
// R8: FAILED — agg+GEMM fusion: 52 KB LDS -> 24% occupancy -> gather BW
//     3.6->2.25 TB/s. Never fuse latency-bound gathers with LDS-heavy MFMA.
// R9: revert fusion; dispatch-count diet (13->11): scan3 folded into
//     consumers (+blk_sum[i>>9]), wt transpose folded into scan2.
// ---------------------------------------------------------------------------

#define NFEAT 128
#define BBITS 8
#define BSZ 256                     // nodes per bucket
#define EPB 4096                    // edges per partition block

union H8 { float4 f4; __half2 h2[4]; };   // 8 halves = 16 B

using half8v = __attribute__((ext_vector_type(8))) _Float16;
using f32x4  = __attribute__((ext_vector_type(4))) float;

// --- Pass 1: per-block LDS histograms; hist2 = [D part | S part], bucket-major ---
__global__ __launch_bounds__(256) void hist_kernel(const int* __restrict__ src,
                                                   const int* __restrict__ dst,
                                                   int* __restrict__ hist2,
                                                   int NB, int nblk, int nh, int E) {
    __shared__ int hd[512], hs[512];
    const int t = threadIdx.x, b = blockIdx.x;
    for (int u = t; u < 512; u += 256) { hd[u] = 0; hs[u] = 0; }
    __syncthreads();
    const int base4 = b * (EPB / 4);
    #pragma unroll
    for (int j = 0; j < 4; ++j) {
        int i4 = base4 + j * 256 + t;
        int e0 = i4 * 4;
        if (e0 + 3 < E) {
            int4 s = ((const int4*)src)[i4];
            int4 d = ((const int4*)dst)[i4];
            atomicAdd(&hs[s.x >> BBITS], 1); atomicAdd(&hs[s.y >> BBITS], 1);
            atomicAdd(&hs[s.z >> BBITS], 1); atomicAdd(&hs[s.w >> BBITS], 1);
            atomicAdd(&hd[d.x >> BBITS], 1); atomicAdd(&hd[d.y >> BBITS], 1);
            atomicAdd(&hd[d.z >> BBITS], 1); atomicAdd(&hd[d.w >> BBITS], 1);
        } else {
            for (int e = e0; e < E && e < e0 + 4; ++e) {
                atomicAdd(&hs[src[e] >> BBITS], 1);
                atomicAdd(&hd[dst[e] >> BBITS], 1);
            }
        }
    }
    __syncthreads();
    for (int u = t; u < NB; u += 256) {
        hist2[u * nblk + b]      = hd[u];
        hist2[nh + u * nblk + b] = hs[u];
    }
}

// --- scan1: block-local exclusive prefixes (512 elems/block) + block sums ---
// Final scanned value of element i = data[i] + scanned_blk_sum[i >> 9].
__global__ __launch_bounds__(256) void scan1_kernel(int* __restrict__ data,
                                                    int* __restrict__ blk_sum, int n) {
    const int tid = threadIdx.x, lane = tid & 63, wid = tid >> 6;  // 4 waves
    const int i2 = blockIdx.x * 256 + tid;
    int a = 0, b = 0;
    if (2 * i2 + 1 < n)      { int2 v = ((const int2*)data)[i2]; a = v.x; b = v.y; }
    else if (2 * i2 < n)     { a = data[2 * i2]; }
    int s = a + b;
    int incl = s;
    #pragma unroll
    for (int off = 1; off < 64; off <<= 1) {
        int t2 = __shfl_up(incl, off, 64);
        if (lane >= off) incl += t2;
    }
    __shared__ int ws[4];
    if (lane == 63) ws[wid] = incl;
    __syncthreads();
    int woff = 0;
    #pragma unroll
    for (int w = 0; w < 3; ++w) if (w < wid) woff += ws[w];
    int pref = woff + incl - s;
    if (2 * i2 < n)     data[2 * i2]     = pref;
    if (2 * i2 + 1 < n) data[2 * i2 + 1] = pref + a;
    if (tid == 0) blk_sum[blockIdx.x] = ws[0] + ws[1] + ws[2] + ws[3];
}

// --- scan2: exclusive scan of block sums; idle threads also do the W
//     transpose/convert (independent work folded in to kill a dispatch) ---
__global__ __launch_bounds__(1024) void scan2_kernel(int* __restrict__ blk, int nb,
                                                     const float* __restrict__ W1,
                                                     const float* __restrict__ W2,
                                                     const float* __restrict__ W3,
                                                     __half* __restrict__ Wt1,
                                                     __half* __restrict__ Wt2,
                                                     __half* __restrict__ Wt3) {
    const int tid = threadIdx.x, lane = tid & 63, wid = tid >> 6;  // 16 waves
    int v = (tid < nb) ? blk[tid] : 0;
    int incl = v;
    #pragma unroll
    for (int off = 1; off < 64; off <<= 1) {
        int t = __shfl_up(incl, off, 64);
        if (lane >= off) incl += t;
    }
    __shared__ int ws[16];
    if (lane == 63) ws[wid] = incl;
    __syncthreads();
    int woff = 0;
    #pragma unroll
    for (int w = 0; w < 15; ++w) if (w < wid) woff += ws[w];
    if (tid < nb) blk[tid] = woff + incl - v;
    // Wt1/Wt2: 16384 each; Wt3: 8192. Total 40960 halves.
    for (int i = tid; i < 16384; i += 1024) {
        int n = i >> 7, k = i & 127;
        Wt1[i] = __float2half(W1[k * 128 + n]);
        Wt2[i] = __float2half(W2[k * 128 + n]);
        if (i < 8192) {
            int n3 = i >> 7, k3 = i & 127;
            Wt3[i] = __float2half(W3[k3 * 64 + n3]);
        }
    }
}

// --- Pass 2: scatter via block-local LDS counting sort -> coalesced run writes ---
__global__ __launch_bounds__(512) void scatter_kernel(const int* __restrict__ src,
                                                      const int* __restrict__ dst,
                                                      const int* __restrict__ hist2,
                                                      const int* __restrict__ blk_sum,
                                                      unsigned int* __restrict__ dstP,
                                                      unsigned char* __restrict__ srcB,
                                                      int NB, int nblk, int nh, int E) {
    __shared__ int hd[512], hs[512], startD[512], startS[512], baseD[512], baseS[512];
    __shared__ int ws[8];
    __shared__ unsigned int   payD[EPB];   // 16 KB
    __shared__ unsigned short kD[EPB];     // 8 KB
    __shared__ unsigned char  sV[EPB];     // 4 KB
    __shared__ unsigned short kS[EPB];     // 8 KB
    const int t = threadIdx.x, b = blockIdx.x;
    const int lane = t & 63, wid = t >> 6;                 // 8 waves
    hd[t] = 0; hs[t] = 0;
    for (int u = t; u < NB; u += 512) {
        int iD = u * nblk + b;
        int iS = nh + u * nblk + b;
        baseD[u] = hist2[iD] + blk_sum[iD >> 9];
        baseS[u] = hist2[iS] + blk_sum[iS >> 9] - E;       // S scanned after D (sum D = E)
    }
    __syncthreads();

    const int e0 = b * EPB;
    const int nE = min(EPB, E - e0);
    int se[8], de[8], rD[8], rS[8];
    const int be = e0 + t * 8;
    if (be + 7 < E) {
        int4 s0 = ((const int4*)src)[(be >> 2)];
        int4 s1 = ((const int4*)src)[(be >> 2) + 1];
        int4 d0 = ((const int4*)dst)[(be >> 2)];
        int4 d1 = ((const int4*)dst)[(be >> 2) + 1];
        se[0]=s0.x; se[1]=s0.y; se[2]=s0.z; se[3]=s0.w;
        se[4]=s1.x; se[5]=s1.y; se[6]=s1.z; se[7]=s1.w;
        de[0]=d0.x; de[1]=d0.y; de[2]=d0.z; de[3]=d0.w;
        de[4]=d1.x; de[5]=d1.y; de[6]=d1.z; de[7]=d1.w;
    } else {
        #pragma unroll
        for (int j = 0; j < 8; ++j) {
            se[j] = (be + j < E) ? src[be + j] : 0;
            de[j] = (be + j < E) ? dst[be + j] : 0;
        }
    }
    #pragma unroll
    for (int j = 0; j < 8; ++j) {
        if (be + j < E) {
            rD[j] = atomicAdd(&hd[de[j] >> BBITS], 1);
            rS[j] = atomicAdd(&hs[se[j] >> BBITS], 1);
        }
    }
    __syncthreads();
    {
        int v = hd[t], incl = v;
        #pragma unroll
        for (int o = 1; o < 64; o <<= 1) {
            int x = __shfl_up(incl, o, 64);
            if (lane >= o) incl += x;
        }
        if (lane == 63) ws[wid] = incl;
        __syncthreads();
        int woff = 0;
        #pragma unroll
        for (int w = 0; w < 7; ++w) if (w < wid) woff += ws[w];
        startD[t] = woff + incl - v;
    }
    __syncthreads();
    {
        int v = hs[t], incl = v;
        #pragma unroll
        for (int o = 1; o < 64; o <<= 1) {
            int x = __shfl_up(incl, o, 64);
            if (lane >= o) incl += x;
        }
        if (lane == 63) ws[wid] = incl;
        __syncthreads();
        int woff = 0;
        #pragma unroll
        for (int w = 0; w < 7; ++w) if (w < wid) woff += ws[w];
        startS[t] = woff + incl - v;
    }
    __syncthreads();
    #pragma unroll
    for (int j = 0; j < 8; ++j) {
        if (be + j < E) {
            int kd = de[j] >> BBITS;
            int p  = startD[kd] + rD[j];
            payD[p] = ((unsigned int)(de[j] & (BSZ - 1)) << 24) | (unsigned int)se[j];
            kD[p]   = (unsigned short)kd;
            int ks = se[j] >> BBITS;
            int q  = startS[ks] + rS[j];
            sV[q] = (unsigned char)(se[j] & (BSZ - 1));
            kS[q] = (unsigned short)ks;
        }
    }
    __syncthreads();
    for (int p = t; p < nE; p += 512) {
        int k = kD[p];
        dstP[baseD[k] + (p - startD[k])] = payD[p];
        int k2 = kS[p];
        srcB[baseS[k2] + (p - startS[k2])] = sV[p];
    }
}

// --- Pass 3: per-bucket CSR finalize + degrees + norms (all LDS) ---
__global__ __launch_bounds__(256) void bucket_kernel(const unsigned int* __restrict__ dstP,
                                                     const unsigned char* __restrict__ srcB,
                                                     const int* __restrict__ hist2,
                                                     const int* __restrict__ blk_sum,
                                                     int* __restrict__ row_ptr,
                                                     int* __restrict__ col_idx,
                                                     float* __restrict__ in_norm,
                                                     float* __restrict__ out_norm,
                                                     int N, int NB, int nblk, int nh, int E) {
    __shared__ int cnt[BSZ], scnt[BSZ], start[BSZ], off[BSZ];
    __shared__ int ws[4];
    const int k = blockIdx.x, t = threadIdx.x;
    const int node0 = k << BBITS;
    cnt[t] = 0; scnt[t] = 0; off[t] = 0;
    __syncthreads();
    auto scanned = [&](int i) { return hist2[i] + blk_sum[i >> 9]; };
    const int bB = scanned(k * nblk);
    const int bE = (k + 1 < NB) ? scanned((k + 1) * nblk) : E;
    const int sB = scanned(nh + k * nblk) - E;
    const int sE = ((k + 1 < NB) ? scanned(nh + (k + 1) * nblk) : 2 * E) - E;
    for (int i = bB + t; i < bE; i += 256) atomicAdd(&cnt[dstP[i] >> 24], 1);
    for (int i = sB + t; i < sE; i += 256) atomicAdd(&scnt[srcB[i]], 1);
    __syncthreads();
    const int lane = t & 63, wid = t >> 6;
    int v = cnt[t];
    int incl = v;
    #pragma unroll
    for (int o = 1; o < 64; o <<= 1) {
        int x = __shfl_up(incl, o, 64);
        if (lane >= o) incl += x;
    }
    if (lane == 63) ws[wid] = incl;
    __syncthreads();
    int woff = 0;
    #pragma unroll
    for (int w = 0; w < 3; ++w) if (w < wid) woff += ws[w];
    start[t] = woff + incl - v;
    {
        int node = node0 + t;
        if (node < N) {
            row_ptr[node] = bB + start[t];
            in_norm[node]  = rsqrtf((float)(v + 1));          // +1 self-loop
            out_norm[node] = rsqrtf((float)(scnt[t] + 1));
        }
    }
    if (k == 0 && t == 0) row_ptr[N] = E;
    __syncthreads();
    for (int i = bB + t; i < bE; i += 256) {
        unsigned int pv = dstP[i];
        int local = pv >> 24;
        int r = atomicAdd(&off[local], 1);
        col_idx[bB + start[local] + r] = (int)(pv & 0xFFFFFFu);
    }
}

// --- MFMA GEMM: h[64 rows x BN] = fp16(x * out_norm) @ W, K = 128 ---
template <int BN, typename XT>
__global__ __launch_bounds__(256) void mfma_gemm_kernel(const XT* __restrict__ x,
                                                        const __half* __restrict__ Wt,
                                                        const float* __restrict__ out_norm,
                                                        __half* __restrict__ h, int n_rows) {
    constexpr int BM = 64;
    constexpr int NT = BN / 16;          // 8 (BN=128) or 4 (BN=64)
    __shared__ __half As[BM][136];
    __shared__ __half Bs[BN][136];
    const int tid  = threadIdx.x;
    const int row0 = blockIdx.x * BM;

    {
        int r  = tid >> 2;                 // 0..63
        int c0 = (tid & 3) * 32;           // 0,32,64,96
        int grow = row0 + r;
        if (grow < n_rows) {
            float norm = out_norm[grow];
            if constexpr (sizeof(XT) == 4) {
                const float* xp = (const float*)x + (size_t)grow * NFEAT + c0;
                #pragma unroll
                for (int j = 0; j < 4; ++j) {
                    float4 p0 = *(const float4*)(xp + j * 8);
                    float4 p1 = *(const float4*)(xp + j * 8 + 4);
                    H8 u;
                    u.h2[0] = __floats2half2_rn(p0.x * norm, p0.y * norm);
                    u.h2[1] = __floats2half2_rn(p0.z * norm, p0.w * norm);
                    u.h2[2] = __floats2half2_rn(p1.x * norm, p1.y * norm);
                    u.h2[3] = __floats2half2_rn(p1.z * norm, p1.w * norm);
                    *(float4*)&As[r][c0 + j * 8] = u.f4;
                }
            } else {
                const __half* xp = (const __half*)x + (size_t)grow * NFEAT + c0;
                #pragma unroll
                for (int j = 0; j < 4; ++j) {
                    H8 u; u.f4 = *(const float4*)(xp + j * 8);
                    #pragma unroll
                    for (int q = 0; q < 4; ++q) {
                        float2 p = __half22float2(u.h2[q]);
                        u.h2[q] = __floats2half2_rn(p.x * norm, p.y * norm);
                    }
                    *(float4*)&As[r][c0 + j * 8] = u.f4;
                }
            }
        } else {
            H8 z; z.f4 = make_float4(0.f, 0.f, 0.f, 0.f);
            #pragma unroll
            for (int j = 0; j < 4; ++j) *(float4*)&As[r][c0 + j * 8] = z.f4;
        }
    }
    {
        constexpr int TPR = 256 / BN;              // threads per row: 2 or 4
        constexpr int CH  = 128 / TPR;             // halves per thread: 64 or 32
        int wr = tid / TPR;
        int wc = (tid % TPR) * CH;
        const __half* wp = Wt + wr * 128 + wc;
        #pragma unroll
        for (int j = 0; j < CH / 8; ++j)
            *(float4*)&Bs[wr][wc + j * 8] = *(const float4*)(wp + j * 8);
    }
    __syncthreads();

    const int lane = tid & 63, wid = tid >> 6;
    const int lr = lane & 15, quad = lane >> 4;
    const int koff = quad * 8;
    f32x4 acc[NT];
    #pragma unroll
    for (int t = 0; t < NT; ++t) acc[t] = (f32x4){0.f, 0.f, 0.f, 0.f};

    #pragma unroll
    for (int ks = 0; ks < 4; ++ks) {
        half8v a = *(const half8v*)&As[wid * 16 + lr][ks * 32 + koff];
        #pragma unroll
        for (int nt = 0; nt < NT; ++nt) {
            half8v b = *(const half8v*)&Bs[nt * 16 + lr][ks * 32 + koff];
            acc[nt] = __builtin_amdgcn_mfma_f32_16x16x32_f16(a, b, acc[nt], 0, 0, 0);
        }
    }

    #pragma unroll
    for (int nt = 0; nt < NT; ++nt) {
        #pragma unroll
        for (int r = 0; r < 4; ++r) {
            int row = row0 + wid * 16 + quad * 4 + r;
            if (row < n_rows)
                h[(size_t)row * BN + nt * 16 + lr] = __float2half(acc[nt][r]);
        }
    }
}

// Gather aggregation + epilogue: out = (sum_in h[src] + h[node]) * in_norm + b [, relu]
template <int DOUT, bool RELU, typename OutT>
__global__ __launch_bounds__(256) void agg_kernel(const __half* __restrict__ h,
                                                  const int* __restrict__ row_ptr,
                                                  const int* __restrict__ col_idx,
                                                  const float* __restrict__ in_norm,
                                                  const float* __restrict__ bias,
                                                  OutT* __restrict__ out, int n) {
    constexpr int TPN = DOUT / 8;      // threads per node (8 halves = 16 B each)
    constexpr int NPB = 256 / TPN;     // nodes per block
    const int tid  = threadIdx.x;
    const int sub  = tid / TPN;
    const int c    = (tid % TPN) * 8;
    const int node = blockIdx.x * NPB + sub;
    if (node >= n) return;

    float acc[8];
    {
        H8 u; u.f4 = *(const float4*)(h + (size_t)node * DOUT + c);  // self-loop
        #pragma unroll
        for (int q = 0; q < 4; ++q) {
            float2 p = __half22float2(u.h2[q]);
            acc[q * 2] = p.x; acc[q * 2 + 1] = p.y;
        }
    }
    int e  = row_ptr[node];
    int e1 = row_ptr[node + 1];
    for (; e + 3 < e1; e += 4) {
        int s0 = col_idx[e], s1 = col_idx[e + 1], s2 = col_idx[e + 2], s3 = col_idx[e + 3];
        H8 u0, u1, u2, u3;
        u0.f4 = *(const float4*)(h + (size_t)s0 * DOUT + c);
        u1.f4 = *(const float4*)(h + (size_t)s1 * DOUT + c);
        u2.f4 = *(const float4*)(h + (size_t)s2 * DOUT + c);
        u3.f4 = *(const float4*)(h + (size_t)s3 * DOUT + c);
        #pragma unroll
        for (int q = 0; q < 4; ++q) {
            float2 p0 = __half22float2(u0.h2[q]);
            float2 p1 = __half22float2(u1.h2[q]);
            float2 p2 = __half22float2(u2.h2[q]);
            float2 p3 = __half22float2(u3.h2[q]);
            acc[q * 2]     += (p0.x + p1.x) + (p2.x + p3.x);
            acc[q * 2 + 1] += (p0.y + p1.y) + (p2.y + p3.y);
        }
    }
    for (; e < e1; ++e) {
        int s0 = col_idx[e];
        H8 u0; u0.f4 = *(const float4*)(h + (size_t)s0 * DOUT + c);
        #pragma unroll
        for (int q = 0; q < 4; ++q) {
            float2 p0 = __half22float2(u0.h2[q]);
            acc[q * 2] += p0.x; acc[q * 2 + 1] += p0.y;
        }
    }
    float inn = in_norm[node];
    float r[8];
    #pragma unroll
    for (int q = 0; q < 8; ++q) {
        r[q] = acc[q] * inn + bias[c + q];
        if (RELU) r[q] = fmaxf(r[q], 0.0f);
    }
    if constexpr (sizeof(OutT) == 2) {
        H8 o;
        #pragma unroll
        for (int q = 0; q < 4; ++q) o.h2[q] = __floats2half2_rn(r[q * 2], r[q * 2 + 1]);
        *(float4*)((__half*)out + (size_t)node * DOUT + c) = o.f4;
    } else {
        float4 o0, o1;
        o0.x=r[0]; o0.y=r[1]; o0.z=r[2]; o0.w=r[3];
        o1.x=r[4]; o1.y=r[5]; o1.z=r[6]; o1.w=r[7];
        *(float4*)((float*)out + (size_t)node * DOUT + c)     = o0;
        *(float4*)((float*)out + (size_t)node * DOUT + c + 4) = o1;
    }
}

extern "C" void kernel_launch(void* const* d_in, const int* in_sizes, int n_in,
                              void* d_out, int out_size, void* d_ws, size_t ws_size,
                              hipStream_t stream) {
    const float* feat = (const float*)d_in[0];
    const int*   src  = (const int*)d_in[1];
    const int*   dst  = (const int*)d_in[2];
    const float* W1   = (const float*)d_in[3];
    const float* b1   = (const float*)d_in[4];
    const float* W2   = (const float*)d_in[5];
    const float* b2   = (const float*)d_in[6];
    const float* W3   = (const float*)d_in[7];
    const float* b3   = (const float*)d_in[8];

    const int N = in_sizes[0] / NFEAT;   // 100000
    const int E = in_sizes[1];           // 1600000

    const int NB   = (N + BSZ - 1) / BSZ;        // 391 buckets
    const int nblk = (E + EPB - 1) / EPB;        // 391 partition blocks
    const int nh   = NB * nblk;                  // hist elements per side
    const int n2   = 2 * nh;                     // concatenated [D|S]
    const int nsb  = (n2 + 511) / 512;           // scan blocks (<= 1024)

    char* ws = (char*)d_ws;
    auto alloc = [&](size_t bytes) {
        char* p = ws;
        ws += (bytes + 255) & ~(size_t)255;
        return p;
    };
    float* out_norm = (float*)alloc((size_t)N * 4);
    float* in_norm  = (float*)alloc((size_t)N * 4);
    int*   row_ptr  = (int*)alloc((size_t)(N + 1) * 4);
    int*   hist2    = (int*)alloc((size_t)n2 * 4);
    int*   blk_sum  = (int*)alloc((size_t)1024 * 4);
    __half* Wt1     = (__half*)alloc((size_t)128 * 128 * 2);
    __half* Wt2     = (__half*)alloc((size_t)128 * 128 * 2);
    __half* Wt3     = (__half*)alloc((size_t)64 * 128 * 2);
    int*   col_idx  = (int*)alloc((size_t)E * 4);
    // hA region also hosts the 2 packed partition arrays (E*4 + E = 8 MB <= 25.6 MB)
    __half* hA      = (__half*)alloc((size_t)N * NFEAT * 2);
    __half* hB      = (__half*)alloc((size_t)N * NFEAT * 2);
    unsigned int*  dstP = (unsigned int*)hA;
    unsigned char* srcB = (unsigned char*)(dstP + E);

    // --- CSR build: hist -> scan1 -> scan2(+wt) -> scatter -> bucket ---
    hist_kernel<<<nblk, 256, 0, stream>>>(src, dst, hist2, NB, nblk, nh, E);
    scan1_kernel<<<nsb, 256, 0, stream>>>(hist2, blk_sum, n2);
    scan2_kernel<<<1, 1024, 0, stream>>>(blk_sum, nsb, W1, W2, W3, Wt1, Wt2, Wt3);
    scatter_kernel<<<nblk, 512, 0, stream>>>(src, dst, hist2, blk_sum, dstP, srcB,
                                             NB, nblk, nh, E);
    bucket_kernel<<<NB, 256, 0, stream>>>(dstP, srcB, hist2, blk_sum, row_ptr, col_idx,
                                          in_norm, out_norm, N, NB, nblk, nh, E);

    const int gb = (N + 63) / 64;
    // layer 1 (x fp32 -> h fp16)
    mfma_gemm_kernel<128, float><<<gb, 256, 0, stream>>>(feat, Wt1, out_norm, hA, N);
    agg_kernel<128, true, __half><<<(N + 15) / 16, 256, 0, stream>>>(hA, row_ptr, col_idx,
                                                                     in_norm, b1, hB, N);
    // layer 2 (fp16 -> fp16)
    mfma_gemm_kernel<128, __half><<<gb, 256, 0, stream>>>(hB, Wt2, out_norm, hA, N);
    agg_kernel<128, true, __half><<<(N + 15) / 16, 256, 0, stream>>>(hA, row_ptr, col_idx,
                                                                     in_norm, b2, hB, N);
    // layer 3 (fp16 -> fp32 d_out, no relu)
    mfma_gemm_kernel<64, __half><<<gb, 256, 0, stream>>>(hB, Wt3, out_norm, hA, N);
    agg_kernel<64, false, float><<<(N + 31) / 32, 256, 0, stream>>>(hA, row_ptr, col_idx,
                                                                    in_norm, b3, (float*)d_out, N);
}